// Round 4
// baseline (281.430 us; speedup 1.0000x reference)
//
#include <hip/hip_runtime.h>
#include <hip/hip_bf16.h>

#define D_MODEL  1280
#define D_BOTTLE 64
#define LN_EPS   1e-5f
#define TM       16
#define HP       1288   // padded h_lds row stride (bf16 elems): 2576 B -> 4-bank shift/row -> free 2-way
#define GP       72     // padded g_lds row stride

typedef __attribute__((ext_vector_type(8))) short short8;
typedef __attribute__((ext_vector_type(4))) float floatx4;

static __device__ inline unsigned short f2bf(float f) {
    __hip_bfloat16 h = __float2bfloat16(f);
    return *reinterpret_cast<unsigned short*>(&h);
}

// Pre-convert fp32 weights -> bf16 in workspace (re-run every launch; ws is re-poisoned)
__global__ void convert_weights(const float* __restrict__ wd, const float* __restrict__ wu,
                                unsigned short* __restrict__ wd_b, unsigned short* __restrict__ wu_b) {
    int i = blockIdx.x * blockDim.x + threadIdx.x;
    if (i < D_MODEL * D_BOTTLE) {
        wd_b[i] = f2bf(wd[i]);
        wu_b[i] = f2bf(wu[i]);
    }
}

__global__ __launch_bounds__(256, 2) void adapter_kernel(
    const float* __restrict__ x,
    const float* __restrict__ gamma, const float* __restrict__ beta,
    const unsigned short* __restrict__ wd_b, const float* __restrict__ b_down,
    const unsigned short* __restrict__ wu_b, const float* __restrict__ b_up,
    float* __restrict__ out)
{
    __shared__ unsigned short h_lds[TM * HP];  // normalized x, bf16
    __shared__ unsigned short g_lds[TM * GP];  // gelu(down) output, bf16

    const int tid  = threadIdx.x;
    const int wave = tid >> 6;
    const int lane = tid & 63;
    const int r0   = blockIdx.x * TM;

    // ---------------- Phase 1: LayerNorm (16 lanes per row, 4 rows per wave) ----------------
    const int rloc = wave * 4 + (lane >> 4);   // row within tile, 0..15
    const int lr   = lane & 15;                // lane within row
    const float* xrow = x + (size_t)(r0 + rloc) * D_MODEL;

    float s = 0.f, sq = 0.f;
    #pragma unroll
    for (int t = 0; t < 20; ++t) {
        float4 v = *reinterpret_cast<const float4*>(xrow + (lr + 16 * t) * 4);
        s  += v.x + v.y + v.z + v.w;
        sq += v.x * v.x + v.y * v.y + v.z * v.z + v.w * v.w;
    }
    #pragma unroll
    for (int m = 1; m < 16; m <<= 1) {
        s  += __shfl_xor(s, m);
        sq += __shfl_xor(sq, m);
    }
    const float mean = s * (1.f / D_MODEL);
    const float var  = sq * (1.f / D_MODEL) - mean * mean;
    const float rinv = rsqrtf(var + LN_EPS);

    #pragma unroll
    for (int t = 0; t < 20; ++t) {
        const int c = (lr + 16 * t) * 4;
        float4 v  = *reinterpret_cast<const float4*>(xrow + c);   // L1/L2 hit (just read)
        float4 g4 = *reinterpret_cast<const float4*>(gamma + c);
        float4 b4 = *reinterpret_cast<const float4*>(beta + c);
        ushort4 pk;
        pk.x = f2bf((v.x - mean) * rinv * g4.x + b4.x);
        pk.y = f2bf((v.y - mean) * rinv * g4.y + b4.y);
        pk.z = f2bf((v.z - mean) * rinv * g4.z + b4.z);
        pk.w = f2bf((v.w - mean) * rinv * g4.w + b4.w);
        *reinterpret_cast<ushort4*>(&h_lds[rloc * HP + c]) = pk;
    }
    __syncthreads();

    // ---------------- Phase 2: down-proj (M=16, N=64, K=1280), wave w owns n-tile w ----------
    const int l15   = lane & 15;
    const int khalf = lane >> 4;       // 0..3
    const int n0    = wave * 16;

    floatx4 acc = {0.f, 0.f, 0.f, 0.f};
    const unsigned short* arow = h_lds + l15 * HP + khalf * 8;
    const unsigned short* brow = wd_b + (size_t)(n0 + l15) * D_MODEL + khalf * 8;
    #pragma unroll 8
    for (int kk = 0; kk < 40; ++kk) {
        short8 a = *reinterpret_cast<const short8*>(arow + kk * 32);
        short8 b = *reinterpret_cast<const short8*>(brow + kk * 32);
        acc = __builtin_amdgcn_mfma_f32_16x16x32_bf16(a, b, acc, 0, 0, 0);
    }

    // ---------------- Phase 3: bias + exact GELU -> g_lds ----------------
    const float bd = b_down[n0 + l15];
    #pragma unroll
    for (int r = 0; r < 4; ++r) {
        const int m = khalf * 4 + r;               // output row
        const float yv = acc[r] + bd;
        const float gv = 0.5f * yv * (1.f + erff(yv * 0.70710678118654752f));
        g_lds[m * GP + n0 + l15] = f2bf(gv);
    }
    __syncthreads();

    // ---------------- Phase 4: up-proj (M=16, N=1280, K=64) + bias + residual ----------------
    // A-fragments (shared across all n-tiles of this wave): load once
    short8 ga0 = *reinterpret_cast<const short8*>(g_lds + l15 * GP +  0 + khalf * 8);
    short8 ga1 = *reinterpret_cast<const short8*>(g_lds + l15 * GP + 32 + khalf * 8);

    const int m_base = khalf * 4;
    #pragma unroll 4
    for (int i = 0; i < 20; ++i) {
        const int d0 = (i * 4 + wave) * 16;
        const int d  = d0 + l15;
        const unsigned short* bptr = wu_b + (size_t)d * D_BOTTLE + khalf * 8;
        short8 b0 = *reinterpret_cast<const short8*>(bptr);
        short8 b1 = *reinterpret_cast<const short8*>(bptr + 32);
        floatx4 acc2 = {0.f, 0.f, 0.f, 0.f};
        acc2 = __builtin_amdgcn_mfma_f32_16x16x32_bf16(ga0, b0, acc2, 0, 0, 0);
        acc2 = __builtin_amdgcn_mfma_f32_16x16x32_bf16(ga1, b1, acc2, 0, 0, 0);
        const float bu = b_up[d];
        #pragma unroll
        for (int r = 0; r < 4; ++r) {
            const size_t idx = (size_t)(r0 + m_base + r) * D_MODEL + d;
            out[idx] = acc2[r] + bu + x[idx];      // x[idx] is an L2 hit
        }
    }
}

extern "C" void kernel_launch(void* const* d_in, const int* in_sizes, int n_in,
                              void* d_out, int out_size, void* d_ws, size_t ws_size,
                              hipStream_t stream) {
    const float* x      = (const float*)d_in[0];
    const float* gamma  = (const float*)d_in[1];
    const float* beta   = (const float*)d_in[2];
    const float* w_down = (const float*)d_in[3];
    const float* b_down = (const float*)d_in[4];
    const float* w_up   = (const float*)d_in[5];
    const float* b_up   = (const float*)d_in[6];
    float* out = (float*)d_out;

    unsigned short* wd_b = (unsigned short*)d_ws;
    unsigned short* wu_b = wd_b + D_MODEL * D_BOTTLE;

    convert_weights<<<(D_MODEL * D_BOTTLE + 255) / 256, 256, 0, stream>>>(w_down, w_up, wd_b, wu_b);

    const int rows = in_sizes[0] / D_MODEL;   // 24000
    adapter_kernel<<<rows / TM, 256, 0, stream>>>(x, gamma, beta, wd_b, b_down, wu_b, b_up, out);
}